// Round 3
// baseline (381.593 us; speedup 1.0000x reference)
//
#include <hip/hip_runtime.h>

typedef _Float16 f16x8 __attribute__((ext_vector_type(8)));
typedef float    f32x4 __attribute__((ext_vector_type(4)));
typedef int      i32x4 __attribute__((ext_vector_type(4)));

#define S_LEN 2048
#define D_KH  64
#define NBH   32                       // B*H
#define QTILE 16
#define NBLK  (NBH * (S_LEN / QTILE))  // 4096
#define THREADS 512                    // 8 waves; each owns a 256-key strip
#define QK_ELEMS (NBH * S_LEN * D_KH)

__device__ __forceinline__ f16x8 cvt8(const float4 a, const float4 b) {
  f16x8 r;
  r[0] = (_Float16)a.x; r[1] = (_Float16)a.y;
  r[2] = (_Float16)a.z; r[3] = (_Float16)a.w;
  r[4] = (_Float16)b.x; r[5] = (_Float16)b.y;
  r[6] = (_Float16)b.z; r[7] = (_Float16)b.w;
  return r;
}

// Prep: K -> f16, q -> f16 pre-scaled by 1/sqrt(64).
__global__ __launch_bounds__(256) void cvt_qk_kernel(
    const float* __restrict__ q, const float* __restrict__ kmat,
    _Float16* __restrict__ qh, _Float16* __restrict__ kh) {
  const long long idx = ((long long)blockIdx.x * 256 + threadIdx.x) * 8;
  float4 q0 = *(const float4*)(q + idx);
  float4 q1 = *(const float4*)(q + idx + 4);
  const float s = 0.125f;
  q0.x *= s; q0.y *= s; q0.z *= s; q0.w *= s;
  q1.x *= s; q1.y *= s; q1.z *= s; q1.w *= s;
  *(f16x8*)(qh + idx) = cvt8(q0, q1);
  const float4 k0 = *(const float4*)(kmat + idx);
  const float4 k1 = *(const float4*)(kmat + idx + 4);
  *(f16x8*)(kh + idx) = cvt8(k0, k1);
}

// Swapped-operand scheme: D = mfma(K_tile, Q_tile) -> D[key][qrow].
// Lane (lo = l&15, g = l>>4), reg r holds score[key = base+16kt+4g+r][qrow = lo].
// All 64 scores of (row lo, wave strip) stay in registers; mask folded at
// production; tiny LDS only for the cross-wave max/sum exchange.
template <bool F16>
__global__ __launch_bounds__(THREADS, 3) void sdpa_probs_kernel(
    const float* __restrict__ qf, const float* __restrict__ kf,
    const _Float16* __restrict__ qh, const _Float16* __restrict__ kh,
    const int* __restrict__ mask, float* __restrict__ out) {
  // XCD-aware swizzle: 512 consecutive nb per XCD (4 heads' f16 panels ~2.5 MiB
  // stay hot in one XCD L2).
  const int bid = (int)blockIdx.x;
  const int nb  = (bid & 7) * (NBLK / 8) + (bid >> 3);
  const int bh  = nb >> 7;
  const int qt  = nb & 127;

  __shared__ float smax[8][16];
  __shared__ float ssum[8][16];

  const int tid = (int)threadIdx.x;
  const int w   = tid >> 6;   // wave 0..7 -> key strip [256w, 256w+256)
  const int l   = tid & 63;
  const int lo  = l & 15;     // q-row within tile
  const int g   = l >> 4;     // key sub-group

  const size_t qk_bh = (size_t)bh * S_LEN * D_KH;
  const size_t obh   = (size_t)bh * S_LEN * S_LEN;
  const int    qrow  = qt * QTILE + lo;
  const size_t orow  = obh + (size_t)qrow * S_LEN;
  const int    cbase = (w << 8) + (g << 2);   // this lane's first key offset

  // ---- B fragment: Q row (pre-scaled), d = 8g..8g+7 and 32+8g.. ----
  f16x8 qb0, qb1;
  if constexpr (F16) {
    const _Float16* qp = qh + qk_bh + (size_t)qrow * D_KH + (g << 3);
    qb0 = *(const f16x8*)qp;
    qb1 = *(const f16x8*)(qp + 32);
  } else {
    const float* qp = qf + qk_bh + (size_t)qrow * D_KH + (g << 3);
    float4 t0 = *(const float4*)(qp);
    float4 t1 = *(const float4*)(qp + 4);
    float4 t2 = *(const float4*)(qp + 32);
    float4 t3 = *(const float4*)(qp + 36);
    const float s = 0.125f;
    t0.x *= s; t0.y *= s; t0.z *= s; t0.w *= s;
    t1.x *= s; t1.y *= s; t1.z *= s; t1.w *= s;
    t2.x *= s; t2.y *= s; t2.z *= s; t2.w *= s;
    t3.x *= s; t3.y *= s; t3.z *= s; t3.w *= s;
    qb0 = cvt8(t0, t1);
    qb1 = cvt8(t2, t3);
  }

  // ---- K loop: 16 kt-tiles of 16 keys; raw masked scores -> sv[64] ----
  float sv[64];
  float mx = -3.0e38f;
  const int* mrow = mask + orow + cbase;
  #pragma unroll
  for (int kt = 0; kt < 16; ++kt) {
    const int keyA = (w << 8) + (kt << 4) + lo;   // A-frag row (key index)
    f16x8 ka0, ka1;
    if constexpr (F16) {
      const _Float16* kp = kh + qk_bh + (size_t)keyA * D_KH + (g << 3);
      ka0 = *(const f16x8*)kp;
      ka1 = *(const f16x8*)(kp + 32);
    } else {
      const float* kp = kf + qk_bh + (size_t)keyA * D_KH + (g << 3);
      ka0 = cvt8(*(const float4*)(kp), *(const float4*)(kp + 4));
      ka1 = cvt8(*(const float4*)(kp + 32), *(const float4*)(kp + 36));
    }
    const i32x4 mv = __builtin_nontemporal_load((const i32x4*)(mrow + (kt << 4)));
    f32x4 acc = {0.f, 0.f, 0.f, 0.f};
    acc = __builtin_amdgcn_mfma_f32_16x16x32_f16(ka0, qb0, acc, 0, 0, 0);
    acc = __builtin_amdgcn_mfma_f32_16x16x32_f16(ka1, qb1, acc, 0, 0, 0);
    const float s0 = mv.x ? -1.0e9f : acc[0];
    const float s1 = mv.y ? -1.0e9f : acc[1];
    const float s2 = mv.z ? -1.0e9f : acc[2];
    const float s3 = mv.w ? -1.0e9f : acc[3];
    sv[4 * kt + 0] = s0; sv[4 * kt + 1] = s1;
    sv[4 * kt + 2] = s2; sv[4 * kt + 3] = s3;
    mx = fmaxf(mx, fmaxf(fmaxf(s0, s1), fmaxf(s2, s3)));
  }

  // ---- Row max: cross-lane (groups) then cross-wave via 1 KiB LDS ----
  mx = fmaxf(mx, __shfl_xor(mx, 16, 64));
  mx = fmaxf(mx, __shfl_xor(mx, 32, 64));
  if (l < 16) smax[w][l] = mx;
  __syncthreads();
  float gmx = smax[0][lo];
  #pragma unroll
  for (int j = 1; j < 8; ++j) gmx = fmaxf(gmx, smax[j][lo]);

  // ---- exp + row sum ----
  float sum = 0.f;
  #pragma unroll
  for (int i = 0; i < 64; ++i) { sv[i] = __expf(sv[i] - gmx); sum += sv[i]; }
  sum += __shfl_xor(sum, 16, 64);
  sum += __shfl_xor(sum, 32, 64);
  if (l < 16) ssum[w][l] = sum;
  __syncthreads();
  float tot = ssum[0][lo];
  #pragma unroll
  for (int j = 1; j < 8; ++j) tot += ssum[j][lo];
  const float inv = 1.0f / tot;

  // ---- Store: 16 x f32x4 (4 consecutive keys/lane); 64B full-line segs ----
  float* op = out + orow + cbase;
  #pragma unroll
  for (int kt = 0; kt < 16; ++kt) {
    f32x4 o = { sv[4 * kt + 0] * inv, sv[4 * kt + 1] * inv,
                sv[4 * kt + 2] * inv, sv[4 * kt + 3] * inv };
    __builtin_nontemporal_store(o, (f32x4*)(op + (kt << 4)));
  }
}

extern "C" void kernel_launch(void* const* d_in, const int* in_sizes, int n_in,
                              void* d_out, int out_size, void* d_ws, size_t ws_size,
                              hipStream_t stream) {
  const float* q    = (const float*)d_in[0];
  const float* kmat = (const float*)d_in[1];
  // d_in[2] = v, unused (reference stops at softmax)
  const int*   mask = (const int*)d_in[3];
  float*       out  = (float*)d_out;

  const size_t need = (size_t)QK_ELEMS * 2 * sizeof(_Float16);
  if (ws_size >= need) {
    _Float16* qh = (_Float16*)d_ws;
    _Float16* kh = qh + QK_ELEMS;
    cvt_qk_kernel<<<dim3(QK_ELEMS / 8 / 256), dim3(256), 0, stream>>>(q, kmat, qh, kh);
    sdpa_probs_kernel<true><<<dim3(NBLK), dim3(THREADS), 0, stream>>>(
        nullptr, nullptr, qh, kh, mask, out);
  } else {
    sdpa_probs_kernel<false><<<dim3(NBLK), dim3(THREADS), 0, stream>>>(
        q, kmat, nullptr, nullptr, mask, out);
  }
}

// Round 4
// 236.160 us; speedup vs baseline: 1.6158x; 1.6158x over previous
//
#include <hip/hip_runtime.h>

typedef _Float16 f16x8 __attribute__((ext_vector_type(8)));
typedef _Float16 f16x4 __attribute__((ext_vector_type(4)));
typedef float    f32x4 __attribute__((ext_vector_type(4)));
typedef int      i32x4 __attribute__((ext_vector_type(4)));

#define S_LEN 2048
#define D_KH  64
#define NBH   32                       // B*H
#define QTILE 16
#define NBLK  (NBH * (S_LEN / QTILE))  // 4096
#define THREADS 512                    // 8 waves
#define QK_ELEMS (NBH * S_LEN * D_KH)

__device__ __forceinline__ f16x8 cvt8(const float4 a, const float4 b) {
  f16x8 r;
  r[0] = (_Float16)a.x; r[1] = (_Float16)a.y;
  r[2] = (_Float16)a.z; r[3] = (_Float16)a.w;
  r[4] = (_Float16)b.x; r[5] = (_Float16)b.y;
  r[6] = (_Float16)b.z; r[7] = (_Float16)b.w;
  return r;
}

// Prep: K -> f16, q -> f16 pre-scaled by 1/sqrt(64).
__global__ __launch_bounds__(256) void cvt_qk_kernel(
    const float* __restrict__ q, const float* __restrict__ kmat,
    _Float16* __restrict__ qh, _Float16* __restrict__ kh) {
  const long long idx = ((long long)blockIdx.x * 256 + threadIdx.x) * 8;
  float4 q0 = *(const float4*)(q + idx);
  float4 q1 = *(const float4*)(q + idx + 4);
  const float s = 0.125f;
  q0.x *= s; q0.y *= s; q0.z *= s; q0.w *= s;
  q1.x *= s; q1.y *= s; q1.z *= s; q1.w *= s;
  *(f16x8*)(qh + idx) = cvt8(q0, q1);
  const float4 k0 = *(const float4*)(kmat + idx);
  const float4 k1 = *(const float4*)(kmat + idx + 4);
  *(f16x8*)(kh + idx) = cvt8(k0, k1);
}

// Softmax over one 2048-wide row whose raw f16 scores sit in LDS (swizzled).
// Masks are pre-fetched in registers. No sv[] array: 3 LDS re-read passes
// (max / exp-sum / scale-store) keep VGPR below 128 for 2 blocks/CU.
__device__ __forceinline__ void softmax_row_lds(
    const _Float16* __restrict__ srow, const i32x4* __restrict__ m,
    const int physx, const int l, float* __restrict__ op) {
  float mx = -3.0e38f;
  #pragma unroll
  for (int i = 0; i < 8; ++i) {
    const int col = (i << 8) + (l << 2);
    const f16x4 h = *(const f16x4*)&srow[col ^ physx];
    mx = fmaxf(mx, m[i].x ? -1.0e9f : (float)h[0]);
    mx = fmaxf(mx, m[i].y ? -1.0e9f : (float)h[1]);
    mx = fmaxf(mx, m[i].z ? -1.0e9f : (float)h[2]);
    mx = fmaxf(mx, m[i].w ? -1.0e9f : (float)h[3]);
  }
  #pragma unroll
  for (int off = 32; off > 0; off >>= 1)
    mx = fmaxf(mx, __shfl_xor(mx, off, 64));
  float sum = 0.f;
  #pragma unroll
  for (int i = 0; i < 8; ++i) {
    const int col = (i << 8) + (l << 2);
    const f16x4 h = *(const f16x4*)&srow[col ^ physx];
    sum += __expf((m[i].x ? -1.0e9f : (float)h[0]) - mx);
    sum += __expf((m[i].y ? -1.0e9f : (float)h[1]) - mx);
    sum += __expf((m[i].z ? -1.0e9f : (float)h[2]) - mx);
    sum += __expf((m[i].w ? -1.0e9f : (float)h[3]) - mx);
  }
  #pragma unroll
  for (int off = 32; off > 0; off >>= 1)
    sum += __shfl_xor(sum, off, 64);
  const float inv = 1.0f / sum;
  #pragma unroll
  for (int i = 0; i < 8; ++i) {
    const int col = (i << 8) + (l << 2);
    const f16x4 h = *(const f16x4*)&srow[col ^ physx];
    f32x4 o = { __expf((m[i].x ? -1.0e9f : (float)h[0]) - mx) * inv,
                __expf((m[i].y ? -1.0e9f : (float)h[1]) - mx) * inv,
                __expf((m[i].z ? -1.0e9f : (float)h[2]) - mx) * inv,
                __expf((m[i].w ? -1.0e9f : (float)h[3]) - mx) * inv };
    __builtin_nontemporal_store(o, (f32x4*)(op + col));
  }
}

template <bool F16>
__global__ __launch_bounds__(THREADS, 4) void sdpa_probs_kernel(
    const float* __restrict__ qf, const float* __restrict__ kf,
    const _Float16* __restrict__ qh, const _Float16* __restrict__ kh,
    const int* __restrict__ mask, float* __restrict__ out) {
  // XCD-aware swizzle: 512 consecutive nb per XCD -> 4 heads' f16 K panels
  // (~2.5 MiB incl. q) hot in one XCD L2.
  const int bid = (int)blockIdx.x;
  const int nb  = (bid & 7) * (NBLK / 8) + (bid >> 3);
  const int bh  = nb >> 7;
  const int qt  = nb & 127;

  __shared__ _Float16 sc[QTILE][S_LEN];  // 64 KiB raw score strip

  const int tid   = (int)threadIdx.x;
  const int w     = tid >> 6;   // wave 0..7
  const int l     = tid & 63;
  const int lo    = l & 15;
  const int g     = l >> 4;
  const int dbase = g << 3;

  const size_t qk_bh = (size_t)bh * S_LEN * D_KH;
  const size_t obh   = (size_t)bh * S_LEN * S_LEN;

  const int rowA = w << 1, rowB = rowA + 1;   // wave w owns rows 2w, 2w+1
  const size_t orowA = obh + (size_t)(qt * QTILE + rowA) * S_LEN;
  const size_t orowB = obh + (size_t)(qt * QTILE + rowB) * S_LEN;

  // ---- Prefetch BOTH rows' masks: HBM latency + traffic lands under
  //      phase 1, so phase 2 is a pure store stream (smooth HBM issue).
  i32x4 mA[8], mB[8];
  {
    const int* mpA = mask + orowA + (l << 2);
    const int* mpB = mask + orowB + (l << 2);
    #pragma unroll
    for (int i = 0; i < 8; ++i) {
      mA[i] = __builtin_nontemporal_load((const i32x4*)(mpA + (i << 8)));
      mB[i] = __builtin_nontemporal_load((const i32x4*)(mpB + (i << 8)));
    }
  }

  // ---- A fragments: q rows (pre-scaled) ----
  f16x8 a0, a1;
  if constexpr (F16) {
    const _Float16* qp = qh + qk_bh + (size_t)(qt * QTILE + lo) * D_KH + dbase;
    a0 = *(const f16x8*)qp;
    a1 = *(const f16x8*)(qp + 32);
  } else {
    const float* qp = qf + qk_bh + (size_t)(qt * QTILE + lo) * D_KH;
    float4 t0 = *(const float4*)(qp + dbase);
    float4 t1 = *(const float4*)(qp + dbase + 4);
    float4 t2 = *(const float4*)(qp + dbase + 32);
    float4 t3 = *(const float4*)(qp + dbase + 36);
    const float s = 0.125f;
    t0.x *= s; t0.y *= s; t0.z *= s; t0.w *= s;
    t1.x *= s; t1.y *= s; t1.z *= s; t1.w *= s;
    t2.x *= s; t2.y *= s; t2.z *= s; t2.w *= s;
    t3.x *= s; t3.y *= s; t3.z *= s; t3.w *= s;
    a0 = cvt8(t0, t1);
    a1 = cvt8(t2, t3);
  }

  // ---- Phase 1: scores via f16 MFMA; wave w owns keys [256w, 256w+256) ----
  #pragma unroll 2
  for (int kt = 0; kt < 16; ++kt) {
    const int kcol = (w << 8) + (kt << 4) + lo;
    f16x8 b0, b1;
    if constexpr (F16) {
      const _Float16* kp = kh + qk_bh + (size_t)kcol * D_KH + dbase;
      b0 = *(const f16x8*)kp;
      b1 = *(const f16x8*)(kp + 32);
    } else {
      const float* kp = kf + qk_bh + (size_t)kcol * D_KH + dbase;
      b0 = cvt8(*(const float4*)(kp), *(const float4*)(kp + 4));
      b1 = cvt8(*(const float4*)(kp + 32), *(const float4*)(kp + 36));
    }
    f32x4 acc = {0.f, 0.f, 0.f, 0.f};
    acc = __builtin_amdgcn_mfma_f32_16x16x32_f16(a0, b0, acc, 0, 0, 0);
    acc = __builtin_amdgcn_mfma_f32_16x16x32_f16(a1, b1, acc, 0, 0, 0);
    // D layout: row = 4g+r, col = lo. XOR-swizzle col bit4 by g -> all 32
    // banks, 2 lanes/bank (free).
    const int phys = kcol ^ (g << 4);
    #pragma unroll
    for (int r = 0; r < 4; ++r)
      sc[(g << 2) + r][phys] = (_Float16)acc[r];
  }

  // Keep prefetched masks live across phase 1 (prevent sinking past barrier).
  #pragma unroll
  for (int i = 0; i < 8; ++i) asm volatile("" :: "v"(mA[i]), "v"(mB[i]));
  __syncthreads();

  // ---- Phase 2: per-row softmax; rowA>>2 == rowB>>2 == w>>1 ----
  const int physx = (w >> 1) << 4;
  softmax_row_lds(&sc[rowA][0], mA, physx, l, out + orowA);
  softmax_row_lds(&sc[rowB][0], mB, physx, l, out + orowB);
}

extern "C" void kernel_launch(void* const* d_in, const int* in_sizes, int n_in,
                              void* d_out, int out_size, void* d_ws, size_t ws_size,
                              hipStream_t stream) {
  const float* q    = (const float*)d_in[0];
  const float* kmat = (const float*)d_in[1];
  // d_in[2] = v, unused (reference stops at softmax)
  const int*   mask = (const int*)d_in[3];
  float*       out  = (float*)d_out;

  const size_t need = (size_t)QK_ELEMS * 2 * sizeof(_Float16);
  if (ws_size >= need) {
    _Float16* qh = (_Float16*)d_ws;
    _Float16* kh = qh + QK_ELEMS;
    cvt_qk_kernel<<<dim3(QK_ELEMS / 8 / 256), dim3(256), 0, stream>>>(q, kmat, qh, kh);
    sdpa_probs_kernel<true><<<dim3(NBLK), dim3(THREADS), 0, stream>>>(
        nullptr, nullptr, qh, kh, mask, out);
  } else {
    sdpa_probs_kernel<false><<<dim3(NBLK), dim3(THREADS), 0, stream>>>(
        q, kmat, nullptr, nullptr, mask, out);
  }
}